// Round 7
// baseline (550.010 us; speedup 1.0000x reference)
//
#include <hip/hip_runtime.h>
#include <hip/hip_bf16.h>
#include <math.h>

#define NS 16
#define H  48
#define TB 128            // edges per block-tile
#define THREADS 256       // 4 waves, wave-private 32-edge sub-tiles

typedef __attribute__((ext_vector_type(8))) short bf16x8;
typedef __attribute__((ext_vector_type(4))) float f32x4;

// ---- LDS (halfword offsets) ----
// A [128][64] swizzled bf16, T [128][64] swizzled bf16, X [128][16] bf16,
// SV [128][4] f32, SLI [128] int.  Total 19712 hw = 39424 B -> 4 blocks/CU.
#define AO   0
#define TO   8192
#define XO   16384
#define SVFI 9216     // float index (hw 18432)
#define SLII 9728     // int index (hw 19456)
#define SMEM_HW 19712

__device__ __forceinline__ short f2bf(float f) {
    unsigned b = __float_as_uint(f);
    unsigned r = (b + 0x7FFFu + ((b >> 16) & 1u)) >> 16;
    return (short)r;
}
__device__ __forceinline__ float bf2f(short s) {
    return __uint_as_float(((unsigned)(unsigned short)s) << 16);
}

// ---------- prep: pack W1/W2 into MFMA B-fragment-linear bf16 ----------
// frag f: 0..2 = W1 col-block fr ; 3..22 = W2 col-block u = f-3.
// layout: wpack[f*1024 + half*512 + lane*8 + i] ; value = W[k][n],
//   n = (f<3?f:f-3)*16 + (lane&15), k = half*32 + (lane>>4)*8 + i, 0 if k>=48.
__global__ __launch_bounds__(256) void prep_kernel(
    const float* __restrict__ fc1_w, const float* __restrict__ fc2_w,
    short* __restrict__ wpack)
{
    int t = blockIdx.x * blockDim.x + threadIdx.x;
    if (t >= 23 * 64) return;
    int f = t >> 6, l = t & 63;
    int fb = (f < 3) ? f : (f - 3);
    int n = fb * 16 + (l & 15);
    const float* W = (f < 3) ? fc1_w : fc2_w;
    int ldw = (f < 3) ? 48 : 320;
    short* dst = wpack + f * 1024 + l * 8;
    #pragma unroll
    for (int half = 0; half < 2; ++half)
        #pragma unroll
        for (int i = 0; i < 8; ++i) {
            int k = half * 32 + (l >> 4) * 8 + i;
            dst[half * 512 + i] = (k < 48) ? f2bf(W[k * ldw + n]) : (short)0;
        }
}

// ---------- main edge kernel ----------
template<bool SLOT>
__global__ __launch_bounds__(THREADS, 4) void edge_mfma_kernel(
    const float* __restrict__ node_attr,
    const float* __restrict__ edge_attr,
    const float* __restrict__ edge_vec,
    const float* __restrict__ fc1_b,
    const float* __restrict__ fc2_b,
    const short* __restrict__ wpack,
    const int*   __restrict__ edge_index,
    float* __restrict__ dst_buf,   // SLOT ? msg[E][32] : out[N][28]
    float* __restrict__ cnt,       // !SLOT
    int*   __restrict__ cursor,    // SLOT
    int E)
{
    __shared__ __align__(16) short smemS[SMEM_HW];
    float* smemF = (float*)smemS;
    int*   smemI = (int*)smemS;
    const int tid = threadIdx.x;
    const int base = blockIdx.x * TB;
    const int l  = tid & 63;
    const int wv = tid >> 6;
    const int g  = l >> 4;
    const int c  = l & 15;
    const int rb = wv * 32;

    // ---- staging: 2 threads per edge; each wave stages only its own 32 rows ----
    {
        const int r = tid >> 1, h = tid & 1;   // r in [rb, rb+32)
        const int e = base + r;
        const int ce = e < E ? e : (E - 1);
        const int dI = edge_index[E + ce];
        const float* ap = edge_attr + (size_t)ce * H + h * 24;
        float4 A0 = *(const float4*)(ap + 0);
        float4 A1 = *(const float4*)(ap + 4);
        float4 A2 = *(const float4*)(ap + 8);
        float4 A3 = *(const float4*)(ap + 12);
        float4 A4 = *(const float4*)(ap + 16);
        float4 A5 = *(const float4*)(ap + 20);
        const float* xp = node_attr + (size_t)dI * NS + h * 8;
        float4 X0 = *(const float4*)(xp + 0);
        float4 X1 = *(const float4*)(xp + 4);
        if (e >= E) {
            A0 = make_float4(0,0,0,0); A1 = A0; A2 = A0; A3 = A0; A4 = A0; A5 = A0;
            X0 = A0; X1 = A0;
        }
        const int s8 = (r & 7) << 3;
        // three 8-hw chunks (swizzled) of this edge's A row
        {
            int a = AO + r * 64 + (((h*3 + 0) << 3) ^ s8);
            *(short4*)&smemS[a + 0] = make_short4(f2bf(A0.x), f2bf(A0.y), f2bf(A0.z), f2bf(A0.w));
            *(short4*)&smemS[a + 4] = make_short4(f2bf(A1.x), f2bf(A1.y), f2bf(A1.z), f2bf(A1.w));
            a = AO + r * 64 + (((h*3 + 1) << 3) ^ s8);
            *(short4*)&smemS[a + 0] = make_short4(f2bf(A2.x), f2bf(A2.y), f2bf(A2.z), f2bf(A2.w));
            *(short4*)&smemS[a + 4] = make_short4(f2bf(A3.x), f2bf(A3.y), f2bf(A3.z), f2bf(A3.w));
            a = AO + r * 64 + (((h*3 + 2) << 3) ^ s8);
            *(short4*)&smemS[a + 0] = make_short4(f2bf(A4.x), f2bf(A4.y), f2bf(A4.z), f2bf(A4.w));
            *(short4*)&smemS[a + 4] = make_short4(f2bf(A5.x), f2bf(A5.y), f2bf(A5.z), f2bf(A5.w));
        }
        // zero pad chunks (k=48..63): h==1 zeros A, h==0 zeros T
        {
            short4 z = make_short4(0,0,0,0);
            int zb = (h ? AO : TO) + r * 64;
            int a6 = zb + ((6 << 3) ^ s8);
            int a7 = zb + ((7 << 3) ^ s8);
            *(short4*)&smemS[a6 + 0] = z; *(short4*)&smemS[a6 + 4] = z;
            *(short4*)&smemS[a7 + 0] = z; *(short4*)&smemS[a7 + 4] = z;
        }
        // x
        *(short4*)&smemS[XO + r * 16 + h * 8 + 0] =
            make_short4(f2bf(X0.x), f2bf(X0.y), f2bf(X0.z), f2bf(X0.w));
        *(short4*)&smemS[XO + r * 16 + h * 8 + 4] =
            make_short4(f2bf(X1.x), f2bf(X1.y), f2bf(X1.z), f2bf(X1.w));
        if (h == 0) {
            int sI = edge_index[ce];
            float vx = 0.f, vy = 0.f, vz = 0.f;
            if (e < E) {
                vx = edge_vec[3 * (size_t)ce + 0];
                vy = edge_vec[3 * (size_t)ce + 1];
                vz = edge_vec[3 * (size_t)ce + 2];
            } else sI = 0;
            float rn = 1.0f / (sqrtf(vx*vx + vy*vy + vz*vz) + 1e-8f);
            const float c1 = 1.7320508075688772f;
            *(float4*)&smemF[SVFI + r * 4] =
                make_float4(c1*vx*rn, c1*vy*rn, c1*vz*rn, __int_as_float(sI));
            if constexpr (SLOT) {
                int slot = 0;
                if (e < E) slot = atomicAdd(cursor + sI, 1);
                smemI[SLII + r] = slot;
            }
        }
    }
    // no barrier: all mutable LDS is wave-private (same-wave LDS ordering,
    // proven correct in rounds 3-6)

    // ---- GEMM1: T = relu(A @ W1 + b1); W1 fragments streamed from L2 ----
    bf16x8 a0[2], a1[2];
    #pragma unroll
    for (int m = 0; m < 2; ++m) {
        int row = rb + m * 16 + c, s8 = (row & 7) << 3;
        a0[m] = *(const bf16x8*)&smemS[AO + row * 64 + ((g * 8) ^ s8)];
        a1[m] = *(const bf16x8*)&smemS[AO + row * 64 + ((32 + g * 8) ^ s8)];
    }
    #pragma unroll
    for (int fr = 0; fr < 3; ++fr) {
        bf16x8 b0 = *(const bf16x8*)(wpack + fr * 1024 + l * 8);
        bf16x8 b1 = *(const bf16x8*)(wpack + fr * 1024 + 512 + l * 8);
        float bia = fc1_b[fr * 16 + c];
        #pragma unroll
        for (int m = 0; m < 2; ++m) {
            f32x4 acc = {0.f, 0.f, 0.f, 0.f};
            acc = __builtin_amdgcn_mfma_f32_16x16x32_bf16(a0[m], b0, acc, 0, 0, 0);
            acc = __builtin_amdgcn_mfma_f32_16x16x32_bf16(a1[m], b1, acc, 0, 0, 0);
            #pragma unroll
            for (int j = 0; j < 4; ++j) {
                int row = rb + m * 16 + g * 4 + j;
                smemS[TO + row * 64 + ((fr * 16 + c) ^ ((row & 7) << 3))] =
                    f2bf(fmaxf(acc[j] + bia, 0.f));
            }
        }
    }

    // ---- fragments for GEMM2 ----
    bf16x8 tf0[2], tf1[2];
    #pragma unroll
    for (int m = 0; m < 2; ++m) {
        int row = rb + m * 16 + c, s8 = (row & 7) << 3;
        tf0[m] = *(const bf16x8*)&smemS[TO + row * 64 + ((g * 8) ^ s8)];
        tf1[m] = *(const bf16x8*)&smemS[TO + row * 64 + ((32 + g * 8) ^ s8)];
    }
    bf16x8 xr0[2][4], xr1[2][4];
    #pragma unroll
    for (int m = 0; m < 2; ++m)
        #pragma unroll
        for (int j = 0; j < 4; ++j) {
            int row = rb + m * 16 + g * 4 + j;
            xr0[m][j] = *(const bf16x8*)&smemS[XO + row * 16];
            xr1[m][j] = *(const bf16x8*)&smemS[XO + row * 16 + 8];
        }

    // ---- GEMM2 (W2 streamed from L2, 1-deep rolling prefetch) + contraction ----
    const short* w2 = wpack + 3 * 1024;
    float o0[2][4] = {{0.f,0.f,0.f,0.f},{0.f,0.f,0.f,0.f}};
    float o1[2][4] = {{0.f,0.f,0.f,0.f},{0.f,0.f,0.f,0.f}};
    bf16x8 nb0 = *(const bf16x8*)(w2 + l * 8);
    bf16x8 nb1 = *(const bf16x8*)(w2 + 512 + l * 8);
    float nbia = fc2_b[c];
    const int s2 = c >> 2;
    #pragma unroll
    for (int u = 0; u < 20; ++u) {
        bf16x8 b0 = nb0, b1 = nb1;
        float bia = nbia;
        if (u < 19) {
            nb0 = *(const bf16x8*)(w2 + (u + 1) * 1024 + l * 8);
            nb1 = *(const bf16x8*)(w2 + (u + 1) * 1024 + 512 + l * 8);
            nbia = fc2_b[(u + 1) * 16 + c];
        }
        #pragma unroll
        for (int m = 0; m < 2; ++m) {
            f32x4 acc = {0.f, 0.f, 0.f, 0.f};
            acc = __builtin_amdgcn_mfma_f32_16x16x32_bf16(tf0[m], b0, acc, 0, 0, 0);
            acc = __builtin_amdgcn_mfma_f32_16x16x32_bf16(tf1[m], b1, acc, 0, 0, 0);
            if (u < 16) {
                #pragma unroll
                for (int j = 0; j < 4; ++j) {
                    float xu = bf2f(u < 8 ? xr0[m][j][u] : xr1[m][j][u - 8]);
                    o0[m][j] = fmaf(xu, acc[j] + bia, o0[m][j]);
                }
            } else {
                const int f = u - 16;
                #pragma unroll
                for (int j = 0; j < 4; ++j) {
                    float e0, e1, e2, e3;
                    if (f < 2) {
                        e0 = bf2f(xr0[m][j][f*4+0]); e1 = bf2f(xr0[m][j][f*4+1]);
                        e2 = bf2f(xr0[m][j][f*4+2]); e3 = bf2f(xr0[m][j][f*4+3]);
                    } else {
                        e0 = bf2f(xr1[m][j][(f-2)*4+0]); e1 = bf2f(xr1[m][j][(f-2)*4+1]);
                        e2 = bf2f(xr1[m][j][(f-2)*4+2]); e3 = bf2f(xr1[m][j][(f-2)*4+3]);
                    }
                    float xu = e0;
                    xu = (s2 == 1) ? e1 : xu;
                    xu = (s2 == 2) ? e2 : xu;
                    xu = (s2 == 3) ? e3 : xu;
                    o1[m][j] = fmaf(xu, acc[j] + bia, o1[m][j]);
                }
            }
        }
    }
    #pragma unroll
    for (int m = 0; m < 2; ++m)
        #pragma unroll
        for (int j = 0; j < 4; ++j) {
            o1[m][j] += __shfl_xor(o1[m][j], 4);
            o1[m][j] += __shfl_xor(o1[m][j], 8);
        }

    // ---- epilogue ----
    const float inv = 0.25f;
    #pragma unroll
    for (int m = 0; m < 2; ++m)
        #pragma unroll
        for (int j = 0; j < 4; ++j) {
            const int r = rb + m*16 + g*4 + j;
            const int e = base + r;
            float4 sv = *(const float4*)&smemF[SVFI + r * 4];
            if constexpr (SLOT) {
                int slot = smemI[SLII + r];
                int lsrc = (g << 4) + (c < 12 ? c / 3 : 0);
                float ov = __shfl(o1[m][j], lsrc);
                int m3 = c - 3 * (c / 3);
                float shm = (m3 == 0) ? sv.x : ((m3 == 1) ? sv.y : sv.z);
                float v2 = (c < 12) ? ov * shm * inv : 0.f;
                if (e < E) {
                    float* mb = dst_buf + (size_t)slot * 32;
                    mb[c] = o0[m][j] * inv;
                    mb[16 + c] = v2;
                }
            } else {
                int srcn = __float_as_int(sv.w);
                if (e < E) {
                    float* ob = dst_buf + (size_t)srcn * 28;
                    atomicAdd(ob + c, o0[m][j] * inv);
                    if (c < 4) {
                        float qq = o1[m][j] * inv;
                        atomicAdd(ob + 16 + 3*c + 0, qq * sv.x);
                        atomicAdd(ob + 16 + 3*c + 1, qq * sv.y);
                        atomicAdd(ob + 16 + 3*c + 2, qq * sv.z);
                    }
                    if (c == 0) atomicAdd(cnt + srcn, 1.0f);
                }
            }
        }
}

__global__ __launch_bounds__(256) void hist_kernel(
    const int* __restrict__ edge_index, int* __restrict__ deg, int E)
{
    int i = blockIdx.x * blockDim.x + threadIdx.x;
    if (i < E) atomicAdd(deg + edge_index[i], 1);
}

__global__ __launch_bounds__(1024) void scan_kernel(
    const int* __restrict__ deg, int* __restrict__ starts,
    int* __restrict__ cursor, int N)
{
    __shared__ int lds[1024];
    int t = threadIdx.x;
    int chunk = (N + 1023) / 1024;
    int lo = t * chunk;
    int hi = lo + chunk; if (hi > N) hi = N;
    int s = 0;
    for (int i = lo; i < hi; ++i) s += deg[i];
    lds[t] = s;
    __syncthreads();
    int v = s;
    for (int off = 1; off < 1024; off <<= 1) {
        int u = (t >= off) ? lds[t - off] : 0;
        __syncthreads();
        v += u;
        lds[t] = v;
        __syncthreads();
    }
    int run = v - s;
    for (int i = lo; i < hi; ++i) {
        starts[i] = run;
        cursor[i] = run;
        run += deg[i];
    }
}

// one wave per node; CSR rows are contiguous -> streaming reads
__global__ __launch_bounds__(256) void sum_kernel(
    const float* __restrict__ msg, const int* __restrict__ starts,
    const int* __restrict__ deg, float* __restrict__ out, int N)
{
    int w = (blockIdx.x * blockDim.x + threadIdx.x) >> 6;
    int l = threadIdx.x & 63;
    int half = l >> 5, ch = l & 31;
    if (w >= N) return;
    int s = starts[w], d = deg[w];
    float acc = 0.f;
    for (int k = half; k < d; k += 2)
        acc += msg[(size_t)(s + k) * 32 + ch];
    acc += __shfl_xor(acc, 32);
    if (l < 28) out[(size_t)w * 28 + l] = acc / fmaxf((float)d, 1.0f);
}

__global__ __launch_bounds__(256) void finalize_kernel(
    float* __restrict__ out, const float* __restrict__ cnt, int total)
{
    int i = blockIdx.x * blockDim.x + threadIdx.x;
    if (i < total) {
        float cv = cnt[i / 28];
        out[i] = out[i] / fmaxf(cv, 1.0f);
    }
}

// compact fp32 fallback (only if workspace is unexpectedly small)
__global__ __launch_bounds__(256) void naive_kernel(
    const float* __restrict__ node_attr, const float* __restrict__ edge_attr,
    const float* __restrict__ edge_vec, const float* __restrict__ fc1_w,
    const float* __restrict__ fc1_b, const float* __restrict__ fc2_w,
    const float* __restrict__ fc2_b, const int* __restrict__ edge_index,
    float* __restrict__ out, float* __restrict__ cnt, int E)
{
    int e = blockIdx.x * blockDim.x + threadIdx.x;
    if (e >= E) return;
    float a[H];
    for (int i = 0; i < H; ++i) a[i] = edge_attr[(size_t)e*H + i];
    int dst = edge_index[E + e];
    float x[NS];
    for (int i = 0; i < NS; ++i) x[i] = node_attr[(size_t)dst*NS + i];
    float o0[NS] = {0}, o1v[4] = {0};
    for (int k = 0; k < H; ++k) {
        float tk = fc1_b[k];
        for (int j = 0; j < H; ++j) tk = fmaf(a[j], fc1_w[j*H + k], tk);
        tk = fmaxf(tk, 0.f);
        const float* row = fc2_w + k*320;
        for (int u = 0; u < NS; ++u) {
            float q = tk * x[u];
            for (int w = 0; w < NS; ++w) o0[w] = fmaf(q, row[u*NS+w], o0[w]);
            for (int v = 0; v < 4; ++v) o1v[v] = fmaf(q, row[256+u*4+v], o1v[v]);
        }
    }
    for (int u = 0; u < NS; ++u) {
        float xu = x[u];
        for (int w = 0; w < NS; ++w) o0[w] = fmaf(xu, fc2_b[u*NS+w], o0[w]);
        for (int v = 0; v < 4; ++v) o1v[v] = fmaf(xu, fc2_b[256+u*4+v], o1v[v]);
    }
    float vx = edge_vec[3*(size_t)e], vy = edge_vec[3*(size_t)e+1], vz = edge_vec[3*(size_t)e+2];
    float rn = 1.0f / (sqrtf(vx*vx+vy*vy+vz*vz) + 1e-8f);
    const float c1 = 1.7320508075688772f;
    float sx = c1*vx*rn, sy = c1*vy*rn, sz = c1*vz*rn;
    int src = edge_index[e];
    float* ob = out + (size_t)src * 28;
    for (int w = 0; w < NS; ++w) atomicAdd(ob + w, o0[w] * 0.25f);
    for (int v = 0; v < 4; ++v) {
        float q = o1v[v] * 0.25f;
        atomicAdd(ob + 16 + 3*v + 0, q * sx);
        atomicAdd(ob + 16 + 3*v + 1, q * sy);
        atomicAdd(ob + 16 + 3*v + 2, q * sz);
    }
    atomicAdd(cnt + src, 1.0f);
}

extern "C" void kernel_launch(void* const* d_in, const int* in_sizes, int n_in,
                              void* d_out, int out_size, void* d_ws, size_t ws_size,
                              hipStream_t stream) {
    const float* node_attr  = (const float*)d_in[0];
    const float* edge_attr  = (const float*)d_in[1];
    const float* edge_vec   = (const float*)d_in[2];
    const float* fc1_w      = (const float*)d_in[3];
    const float* fc1_b      = (const float*)d_in[4];
    const float* fc2_w      = (const float*)d_in[5];
    const float* fc2_b      = (const float*)d_in[6];
    const int*   edge_index = (const int*)d_in[7];

    int E = in_sizes[2] / 3;      // 400000
    int N = in_sizes[0] / NS;     // 50000
    float* out = (float*)d_out;
    int nblk = (E + TB - 1) / TB;

    size_t msg_b  = (size_t)E * 32 * sizeof(float);
    size_t ints_b = 3 * (size_t)N * sizeof(int);
    size_t wpk_b  = 23 * 1024 * sizeof(short);
    size_t need   = msg_b + ints_b + wpk_b;

    if (ws_size >= need) {
        float* msg  = (float*)d_ws;
        int* ip     = (int*)((char*)d_ws + msg_b);
        int* deg    = ip;
        int* starts = ip + N;
        int* cursor = ip + 2 * N;
        short* wpack = (short*)((char*)d_ws + msg_b + ints_b);

        hipMemsetAsync(deg, 0, (size_t)N * sizeof(int), stream);
        prep_kernel<<<6, 256, 0, stream>>>(fc1_w, fc2_w, wpack);
        hist_kernel<<<(E + 255) / 256, 256, 0, stream>>>(edge_index, deg, E);
        scan_kernel<<<1, 1024, 0, stream>>>(deg, starts, cursor, N);
        edge_mfma_kernel<true><<<nblk, THREADS, 0, stream>>>(
            node_attr, edge_attr, edge_vec, fc1_b, fc2_b, wpack,
            edge_index, msg, nullptr, cursor, E);
        sum_kernel<<<((size_t)N * 64 + 255) / 256, 256, 0, stream>>>(
            msg, starts, deg, out, N);
    } else {
        float* cnt = (float*)d_ws;
        hipMemsetAsync(d_out, 0, (size_t)out_size * sizeof(float), stream);
        hipMemsetAsync(d_ws, 0, (size_t)N * sizeof(float), stream);
        naive_kernel<<<(E + 255) / 256, 256, 0, stream>>>(
            node_attr, edge_attr, edge_vec, fc1_w, fc1_b, fc2_w, fc2_b,
            edge_index, out, cnt, E);
        int total = N * 28;
        finalize_kernel<<<(total + 255) / 256, 256, 0, stream>>>(out, cnt, total);
    }
}

// Round 8
// 226.103 us; speedup vs baseline: 2.4326x; 2.4326x over previous
//
#include <hip/hip_runtime.h>
#include <hip/hip_bf16.h>
#include <math.h>

#define NS 16
#define H  48
#define TB 128            // edges per block-tile
#define THREADS 256       // 4 waves; wave-private 32-edge sub-tiles

typedef __attribute__((ext_vector_type(8))) short bf16x8;
typedef __attribute__((ext_vector_type(4))) float f32x4;

// ---- LDS layout ----
// hw offsets:
//   WO   [23 frag][2 half][64 lane][8] bf16 fragment-linear weights (47104 B)
//   ATO  [128][64] bf16: A (staging+GEMM1) -> T (GEMM1 out/GEMM2 in) -> msg f32[128][32]
//   XO   [128][16] bf16 gathered node features
// float idx: SVFI [128][4] {shx,shy,shz,src}; B1F[48]; B2F[320]
// int idx:   SLII [128] CSR slot
#define WO    0
#define ATO   23552
#define XO    31744
#define SVFI  16896
#define SLII  17408
#define B1F   17536
#define B2F   17584
#define MSGF  11776      // float idx of ATO
#define SMEM_HW 35808    // 71616 B -> 2 blocks/CU

__device__ __forceinline__ short f2bf(float f) {
    unsigned b = __float_as_uint(f);
    unsigned r = (b + 0x7FFFu + ((b >> 16) & 1u)) >> 16;
    return (short)r;
}
__device__ __forceinline__ float bf2f(short s) {
    return __uint_as_float(((unsigned)(unsigned short)s) << 16);
}

// ---------- prep: pack W1/W2 into MFMA B-fragment-linear bf16 ----------
// frag f: 0..2 = W1 col-block ; 3..22 = W2 col-block u=f-3.
// wpack[f*1024 + half*512 + lane*8 + i] = W[k][n], n=fb*16+(lane&15),
//   k = half*32 + (lane>>4)*8 + i, zero for k>=48.
__global__ __launch_bounds__(256) void prep_kernel(
    const float* __restrict__ fc1_w, const float* __restrict__ fc2_w,
    short* __restrict__ wpack)
{
    int t = blockIdx.x * blockDim.x + threadIdx.x;
    if (t >= 23 * 64) return;
    int f = t >> 6, l = t & 63;
    int fb = (f < 3) ? f : (f - 3);
    int n = fb * 16 + (l & 15);
    const float* W = (f < 3) ? fc1_w : fc2_w;
    int ldw = (f < 3) ? 48 : 320;
    short* dst = wpack + f * 1024 + l * 8;
    #pragma unroll
    for (int half = 0; half < 2; ++half)
        #pragma unroll
        for (int i = 0; i < 8; ++i) {
            int k = half * 32 + (l >> 4) * 8 + i;
            dst[half * 512 + i] = (k < 48) ? f2bf(W[k * ldw + n]) : (short)0;
        }
}

// ---------- main edge kernel ----------
__global__ __launch_bounds__(THREADS, 2) void edge_mfma_kernel(
    const float* __restrict__ node_attr,
    const float* __restrict__ edge_attr,
    const float* __restrict__ edge_vec,
    const float* __restrict__ fc1_b,
    const float* __restrict__ fc2_b,
    const short* __restrict__ wpack,
    const int*   __restrict__ edge_index,
    float* __restrict__ msg,       // [E][32] CSR-ordered messages
    int*   __restrict__ cursor,
    int E)
{
    __shared__ __align__(16) short smemS[SMEM_HW];
    float* smemF = (float*)smemS;
    int*   smemI = (int*)smemS;
    const int tid = threadIdx.x;
    const int base = blockIdx.x * TB;
    const int l  = tid & 63;
    const int wv = tid >> 6;
    const int g  = l >> 4;
    const int c  = l & 15;
    const int rb = wv * 32;

    // ---- W + bias staging: prepacked -> linear copy (cross-wave, needs barrier)
    for (int idx = tid; idx < 2944; idx += THREADS)
        *(float4*)&smemS[idx * 8] = ((const float4*)wpack)[idx];
    if (tid < 48) smemF[B1F + tid] = fc1_b[tid];
    for (int idx = tid; idx < 320; idx += THREADS) smemF[B2F + idx] = fc2_b[idx];

    // ---- per-edge staging: 2 threads/edge, wave-private rows ----
    {
        const int r = tid >> 1, h = tid & 1;   // wave wv stages rows [rb, rb+32)
        const int e = base + r;
        const int ce = e < E ? e : (E - 1);
        const int dI = edge_index[E + ce];
        const float* ap = edge_attr + (size_t)ce * H + h * 24;
        float4 A0 = *(const float4*)(ap + 0);
        float4 A1 = *(const float4*)(ap + 4);
        float4 A2 = *(const float4*)(ap + 8);
        float4 A3 = *(const float4*)(ap + 12);
        float4 A4 = *(const float4*)(ap + 16);
        float4 A5 = *(const float4*)(ap + 20);
        const float* xp = node_attr + (size_t)dI * NS + h * 8;
        float4 X0 = *(const float4*)(xp + 0);
        float4 X1 = *(const float4*)(xp + 4);
        if (e >= E) {
            A0 = make_float4(0,0,0,0); A1 = A0; A2 = A0; A3 = A0; A4 = A0; A5 = A0;
            X0 = A0; X1 = A0;
        }
        const int s8 = (r & 7) << 3;
        int a = ATO + r * 64 + (((h*3 + 0) << 3) ^ s8);
        *(short4*)&smemS[a + 0] = make_short4(f2bf(A0.x), f2bf(A0.y), f2bf(A0.z), f2bf(A0.w));
        *(short4*)&smemS[a + 4] = make_short4(f2bf(A1.x), f2bf(A1.y), f2bf(A1.z), f2bf(A1.w));
        a = ATO + r * 64 + (((h*3 + 1) << 3) ^ s8);
        *(short4*)&smemS[a + 0] = make_short4(f2bf(A2.x), f2bf(A2.y), f2bf(A2.z), f2bf(A2.w));
        *(short4*)&smemS[a + 4] = make_short4(f2bf(A3.x), f2bf(A3.y), f2bf(A3.z), f2bf(A3.w));
        a = ATO + r * 64 + (((h*3 + 2) << 3) ^ s8);
        *(short4*)&smemS[a + 0] = make_short4(f2bf(A4.x), f2bf(A4.y), f2bf(A4.z), f2bf(A4.w));
        *(short4*)&smemS[a + 4] = make_short4(f2bf(A5.x), f2bf(A5.y), f2bf(A5.z), f2bf(A5.w));
        // zero K-pad cols 48..63 (chunk 6+h); T inherits these zeros
        {
            short4 z = make_short4(0,0,0,0);
            int az = ATO + r * 64 + (((6 + h) << 3) ^ s8);
            *(short4*)&smemS[az + 0] = z; *(short4*)&smemS[az + 4] = z;
        }
        *(short4*)&smemS[XO + r * 16 + h * 8 + 0] =
            make_short4(f2bf(X0.x), f2bf(X0.y), f2bf(X0.z), f2bf(X0.w));
        *(short4*)&smemS[XO + r * 16 + h * 8 + 4] =
            make_short4(f2bf(X1.x), f2bf(X1.y), f2bf(X1.z), f2bf(X1.w));
        if (h == 0) {
            int sI = edge_index[ce];
            float vx = 0.f, vy = 0.f, vz = 0.f;
            if (e < E) {
                vx = edge_vec[3 * (size_t)ce + 0];
                vy = edge_vec[3 * (size_t)ce + 1];
                vz = edge_vec[3 * (size_t)ce + 2];
            } else sI = 0;
            float rn = 1.0f / (sqrtf(vx*vx + vy*vy + vz*vz) + 1e-8f);
            const float c1 = 1.7320508075688772f;
            *(float4*)&smemF[SVFI + r * 4] =
                make_float4(c1*vx*rn, c1*vy*rn, c1*vz*rn, __int_as_float(sI));
            int slot = 0;
            if (e < E) slot = atomicAdd(cursor + sI, 1);
            smemI[SLII + r] = slot;
        }
    }
    __syncthreads();   // covers W/bias staging only; everything else wave-private

    // ---- GEMM1: T = relu(A @ W1 + b1) ----
    bf16x8 a0[2], a1[2];
    #pragma unroll
    for (int m = 0; m < 2; ++m) {
        int row = rb + m * 16 + c, s8 = (row & 7) << 3;
        a0[m] = *(const bf16x8*)&smemS[ATO + row * 64 + ((g * 8) ^ s8)];
        a1[m] = *(const bf16x8*)&smemS[ATO + row * 64 + ((32 + g * 8) ^ s8)];
    }
    #pragma unroll
    for (int fr = 0; fr < 3; ++fr) {
        bf16x8 b0 = *(const bf16x8*)&smemS[WO + fr * 1024 + l * 8];
        bf16x8 b1 = *(const bf16x8*)&smemS[WO + fr * 1024 + 512 + l * 8];
        float bia = smemF[B1F + fr * 16 + c];
        #pragma unroll
        for (int m = 0; m < 2; ++m) {
            f32x4 acc = {0.f, 0.f, 0.f, 0.f};
            acc = __builtin_amdgcn_mfma_f32_16x16x32_bf16(a0[m], b0, acc, 0, 0, 0);
            acc = __builtin_amdgcn_mfma_f32_16x16x32_bf16(a1[m], b1, acc, 0, 0, 0);
            #pragma unroll
            for (int j = 0; j < 4; ++j) {
                int row = rb + m * 16 + g * 4 + j;
                smemS[ATO + row * 64 + ((fr * 16 + c) ^ ((row & 7) << 3))] =
                    f2bf(fmaxf(acc[j] + bia, 0.f));
            }
        }
    }

    // ---- fragments for GEMM2 ----
    bf16x8 tf0[2], tf1[2];
    #pragma unroll
    for (int m = 0; m < 2; ++m) {
        int row = rb + m * 16 + c, s8 = (row & 7) << 3;
        tf0[m] = *(const bf16x8*)&smemS[ATO + row * 64 + ((g * 8) ^ s8)];
        tf1[m] = *(const bf16x8*)&smemS[ATO + row * 64 + ((32 + g * 8) ^ s8)];
    }
    bf16x8 xr0[2][4], xr1[2][4];
    #pragma unroll
    for (int m = 0; m < 2; ++m)
        #pragma unroll
        for (int j = 0; j < 4; ++j) {
            int row = rb + m * 16 + g * 4 + j;
            xr0[m][j] = *(const bf16x8*)&smemS[XO + row * 16];
            xr1[m][j] = *(const bf16x8*)&smemS[XO + row * 16 + 8];
        }

    // ---- GEMM2 + fused contraction with x (W2 fragments from LDS) ----
    float o0[2][4] = {{0.f,0.f,0.f,0.f},{0.f,0.f,0.f,0.f}};
    float o1[2][4] = {{0.f,0.f,0.f,0.f},{0.f,0.f,0.f,0.f}};
    const int s2 = c >> 2;
    #pragma unroll
    for (int u = 0; u < 20; ++u) {
        bf16x8 b0 = *(const bf16x8*)&smemS[WO + (3 + u) * 1024 + l * 8];
        bf16x8 b1 = *(const bf16x8*)&smemS[WO + (3 + u) * 1024 + 512 + l * 8];
        float bia = smemF[B2F + u * 16 + c];
        #pragma unroll
        for (int m = 0; m < 2; ++m) {
            f32x4 acc = {0.f, 0.f, 0.f, 0.f};
            acc = __builtin_amdgcn_mfma_f32_16x16x32_bf16(tf0[m], b0, acc, 0, 0, 0);
            acc = __builtin_amdgcn_mfma_f32_16x16x32_bf16(tf1[m], b1, acc, 0, 0, 0);
            if (u < 16) {
                #pragma unroll
                for (int j = 0; j < 4; ++j) {
                    float xu = bf2f(u < 8 ? xr0[m][j][u] : xr1[m][j][u - 8]);
                    o0[m][j] = fmaf(xu, acc[j] + bia, o0[m][j]);
                }
            } else {
                const int f = u - 16;
                #pragma unroll
                for (int j = 0; j < 4; ++j) {
                    float e0, e1, e2, e3;
                    if (f < 2) {
                        e0 = bf2f(xr0[m][j][f*4+0]); e1 = bf2f(xr0[m][j][f*4+1]);
                        e2 = bf2f(xr0[m][j][f*4+2]); e3 = bf2f(xr0[m][j][f*4+3]);
                    } else {
                        e0 = bf2f(xr1[m][j][(f-2)*4+0]); e1 = bf2f(xr1[m][j][(f-2)*4+1]);
                        e2 = bf2f(xr1[m][j][(f-2)*4+2]); e3 = bf2f(xr1[m][j][(f-2)*4+3]);
                    }
                    float xu = e0;
                    xu = (s2 == 1) ? e1 : xu;
                    xu = (s2 == 2) ? e2 : xu;
                    xu = (s2 == 3) ? e3 : xu;
                    o1[m][j] = fmaf(xu, acc[j] + bia, o1[m][j]);
                }
            }
        }
    }
    #pragma unroll
    for (int m = 0; m < 2; ++m)
        #pragma unroll
        for (int j = 0; j < 4; ++j) {
            o1[m][j] += __shfl_xor(o1[m][j], 4);
            o1[m][j] += __shfl_xor(o1[m][j], 8);
        }

    // ---- epilogue: transpose messages through LDS (A region, now dead) ----
    const float inv = 0.25f;
    #pragma unroll
    for (int m = 0; m < 2; ++m)
        #pragma unroll
        for (int j = 0; j < 4; ++j) {
            const int r = rb + m*16 + g*4 + j;
            float4 sv = *(const float4*)&smemF[SVFI + r * 4];
            int lsrc = (g << 4) + (c < 12 ? c / 3 : 0);
            float ov = __shfl(o1[m][j], lsrc);
            int m3 = c - 3 * (c / 3);
            float shm = (m3 == 0) ? sv.x : ((m3 == 1) ? sv.y : sv.z);
            float v2 = (c < 12) ? ov * shm * inv : 0.f;
            smemF[MSGF + r * 32 + c]      = o0[m][j] * inv;
            smemF[MSGF + r * 32 + 16 + c] = v2;
        }

    // ---- full-line stores: 8 lanes x float4 = one fully-dirty 128B line/edge ----
    #pragma unroll
    for (int it = 0; it < 4; ++it) {
        int r2 = rb + it * 8 + (l >> 3);
        int ch = (l & 7) * 4;
        int e2 = base + r2;
        int slot = smemI[SLII + r2];
        float4 val = *(const float4*)&smemF[MSGF + r2 * 32 + ch];
        if (e2 < E) *(float4*)(msg + (size_t)slot * 32 + ch) = val;
    }
}

__global__ __launch_bounds__(256) void hist_kernel(
    const int* __restrict__ edge_index, int* __restrict__ deg, int E)
{
    int i = blockIdx.x * blockDim.x + threadIdx.x;
    if (i < E) atomicAdd(deg + edge_index[i], 1);
}

__global__ __launch_bounds__(1024) void scan_kernel(
    const int* __restrict__ deg, int* __restrict__ starts,
    int* __restrict__ cursor, int N)
{
    __shared__ int lds[1024];
    int t = threadIdx.x;
    int chunk = (N + 1023) / 1024;
    int lo = t * chunk;
    int hi = lo + chunk; if (hi > N) hi = N;
    int s = 0;
    for (int i = lo; i < hi; ++i) s += deg[i];
    lds[t] = s;
    __syncthreads();
    int v = s;
    for (int off = 1; off < 1024; off <<= 1) {
        int u = (t >= off) ? lds[t - off] : 0;
        __syncthreads();
        v += u;
        lds[t] = v;
        __syncthreads();
    }
    int run = v - s;
    for (int i = lo; i < hi; ++i) {
        starts[i] = run;
        cursor[i] = run;
        run += deg[i];
    }
}

// one wave per node; CSR rows contiguous -> streaming reads
__global__ __launch_bounds__(256) void sum_kernel(
    const float* __restrict__ msg, const int* __restrict__ starts,
    const int* __restrict__ deg, float* __restrict__ out, int N)
{
    int w = (blockIdx.x * blockDim.x + threadIdx.x) >> 6;
    int l = threadIdx.x & 63;
    int half = l >> 5, ch = l & 31;
    if (w >= N) return;
    int s = starts[w], d = deg[w];
    float acc = 0.f;
    for (int k = half; k < d; k += 2)
        acc += msg[(size_t)(s + k) * 32 + ch];
    acc += __shfl_xor(acc, 32);
    if (l < 28) out[(size_t)w * 28 + l] = acc / fmaxf((float)d, 1.0f);
}

__global__ __launch_bounds__(256) void finalize_kernel(
    float* __restrict__ out, const float* __restrict__ cnt, int total)
{
    int i = blockIdx.x * blockDim.x + threadIdx.x;
    if (i < total) {
        float cv = cnt[i / 28];
        out[i] = out[i] / fmaxf(cv, 1.0f);
    }
}

// compact fp32 fallback (only if workspace is unexpectedly small)
__global__ __launch_bounds__(256) void naive_kernel(
    const float* __restrict__ node_attr, const float* __restrict__ edge_attr,
    const float* __restrict__ edge_vec, const float* __restrict__ fc1_w,
    const float* __restrict__ fc1_b, const float* __restrict__ fc2_w,
    const float* __restrict__ fc2_b, const int* __restrict__ edge_index,
    float* __restrict__ out, float* __restrict__ cnt, int E)
{
    int e = blockIdx.x * blockDim.x + threadIdx.x;
    if (e >= E) return;
    float a[H];
    for (int i = 0; i < H; ++i) a[i] = edge_attr[(size_t)e*H + i];
    int dst = edge_index[E + e];
    float x[NS];
    for (int i = 0; i < NS; ++i) x[i] = node_attr[(size_t)dst*NS + i];
    float o0[NS] = {0}, o1v[4] = {0};
    for (int k = 0; k < H; ++k) {
        float tk = fc1_b[k];
        for (int j = 0; j < H; ++j) tk = fmaf(a[j], fc1_w[j*H + k], tk);
        tk = fmaxf(tk, 0.f);
        const float* row = fc2_w + k*320;
        for (int u = 0; u < NS; ++u) {
            float q = tk * x[u];
            for (int w = 0; w < NS; ++w) o0[w] = fmaf(q, row[u*NS+w], o0[w]);
            for (int v = 0; v < 4; ++v) o1v[v] = fmaf(q, row[256+u*4+v], o1v[v]);
        }
    }
    for (int u = 0; u < NS; ++u) {
        float xu = x[u];
        for (int w = 0; w < NS; ++w) o0[w] = fmaf(xu, fc2_b[u*NS+w], o0[w]);
        for (int v = 0; v < 4; ++v) o1v[v] = fmaf(xu, fc2_b[256+u*4+v], o1v[v]);
    }
    float vx = edge_vec[3*(size_t)e], vy = edge_vec[3*(size_t)e+1], vz = edge_vec[3*(size_t)e+2];
    float rn = 1.0f / (sqrtf(vx*vx+vy*vy+vz*vz) + 1e-8f);
    const float c1 = 1.7320508075688772f;
    float sx = c1*vx*rn, sy = c1*vy*rn, sz = c1*vz*rn;
    int src = edge_index[e];
    float* ob = out + (size_t)src * 28;
    for (int w = 0; w < NS; ++w) atomicAdd(ob + w, o0[w] * 0.25f);
    for (int v = 0; v < 4; ++v) {
        float q = o1v[v] * 0.25f;
        atomicAdd(ob + 16 + 3*v + 0, q * sx);
        atomicAdd(ob + 16 + 3*v + 1, q * sy);
        atomicAdd(ob + 16 + 3*v + 2, q * sz);
    }
    atomicAdd(cnt + src, 1.0f);
}

extern "C" void kernel_launch(void* const* d_in, const int* in_sizes, int n_in,
                              void* d_out, int out_size, void* d_ws, size_t ws_size,
                              hipStream_t stream) {
    const float* node_attr  = (const float*)d_in[0];
    const float* edge_attr  = (const float*)d_in[1];
    const float* edge_vec   = (const float*)d_in[2];
    const float* fc1_w      = (const float*)d_in[3];
    const float* fc1_b      = (const float*)d_in[4];
    const float* fc2_w      = (const float*)d_in[5];
    const float* fc2_b      = (const float*)d_in[6];
    const int*   edge_index = (const int*)d_in[7];

    int E = in_sizes[2] / 3;      // 400000
    int N = in_sizes[0] / NS;     // 50000
    float* out = (float*)d_out;
    int nblk = (E + TB - 1) / TB;

    size_t msg_b  = (size_t)E * 32 * sizeof(float);
    size_t ints_b = 3 * (size_t)N * sizeof(int);
    size_t wpk_b  = 23 * 1024 * sizeof(short);
    size_t need   = msg_b + ints_b + wpk_b;

    if (ws_size >= need) {
        float* msg  = (float*)d_ws;
        int* ip     = (int*)((char*)d_ws + msg_b);
        int* deg    = ip;
        int* starts = ip + N;
        int* cursor = ip + 2 * N;
        short* wpack = (short*)((char*)d_ws + msg_b + ints_b);

        hipMemsetAsync(deg, 0, (size_t)N * sizeof(int), stream);
        prep_kernel<<<6, 256, 0, stream>>>(fc1_w, fc2_w, wpack);
        hist_kernel<<<(E + 255) / 256, 256, 0, stream>>>(edge_index, deg, E);
        scan_kernel<<<1, 1024, 0, stream>>>(deg, starts, cursor, N);
        edge_mfma_kernel<<<nblk, THREADS, 0, stream>>>(
            node_attr, edge_attr, edge_vec, fc1_b, fc2_b, wpack,
            edge_index, msg, cursor, E);
        sum_kernel<<<((size_t)N * 64 + 255) / 256, 256, 0, stream>>>(
            msg, starts, deg, out, N);
    } else {
        float* cnt = (float*)d_ws;
        hipMemsetAsync(d_out, 0, (size_t)out_size * sizeof(float), stream);
        hipMemsetAsync(d_ws, 0, (size_t)N * sizeof(float), stream);
        naive_kernel<<<(E + 255) / 256, 256, 0, stream>>>(
            node_attr, edge_attr, edge_vec, fc1_w, fc1_b, fc2_w, fc2_b,
            edge_index, out, cnt, E);
        int total = N * 28;
        finalize_kernel<<<(total + 255) / 256, 256, 0, stream>>>(out, cnt, total);
    }
}

// Round 9
// 126.773 us; speedup vs baseline: 4.3386x; 1.7835x over previous
//
#include <hip/hip_runtime.h>
#include <hip/hip_bf16.h>
#include <math.h>

#define NS 16
#define H  48
#define TB 128            // edges per block-tile
#define THREADS 256       // 4 waves; wave-private 32-edge sub-tiles

typedef __attribute__((ext_vector_type(8))) short bf16x8;
typedef __attribute__((ext_vector_type(4))) float f32x4;

// ---- LDS layout ----
// hw offsets:
//   WO   [23 frag][2 half][64 lane][8] bf16 fragment-linear weights (47104 B)
//   ATO  [128][64] bf16: A (staging+GEMM1) -> T (GEMM1 out/GEMM2 in) -> msg f32[128][32]
//   XO   [128][16] bf16 gathered node features
// float idx: SVFI [128][4] {shx,shy,shz,src}; B1F[48]; B2F[320]
// int idx:   SLII [128] CSR slot
#define WO    0
#define ATO   23552
#define XO    31744
#define SVFI  16896
#define SLII  17408
#define B1F   17536
#define B2F   17584
#define MSGF  11776      // float idx of ATO
#define SMEM_HW 35808    // 71616 B -> 2 blocks/CU

__device__ __forceinline__ short f2bf(float f) {
    unsigned b = __float_as_uint(f);
    unsigned r = (b + 0x7FFFu + ((b >> 16) & 1u)) >> 16;
    return (short)r;
}
__device__ __forceinline__ float bf2f(short s) {
    return __uint_as_float(((unsigned)(unsigned short)s) << 16);
}

// ---------- prep: pack W1/W2 into MFMA B-fragment-linear bf16 ----------
__global__ __launch_bounds__(256) void prep_kernel(
    const float* __restrict__ fc1_w, const float* __restrict__ fc2_w,
    short* __restrict__ wpack)
{
    int t = blockIdx.x * blockDim.x + threadIdx.x;
    if (t >= 23 * 64) return;
    int f = t >> 6, l = t & 63;
    int fb = (f < 3) ? f : (f - 3);
    int n = fb * 16 + (l & 15);
    const float* W = (f < 3) ? fc1_w : fc2_w;
    int ldw = (f < 3) ? 48 : 320;
    short* dst = wpack + f * 1024 + l * 8;
    #pragma unroll
    for (int half = 0; half < 2; ++half)
        #pragma unroll
        for (int i = 0; i < 8; ++i) {
            int k = half * 32 + (l >> 4) * 8 + i;
            dst[half * 512 + i] = (k < 48) ? f2bf(W[k * ldw + n]) : (short)0;
        }
}

// ---------- main edge kernel (unchanged from round 8) ----------
__global__ __launch_bounds__(THREADS, 2) void edge_mfma_kernel(
    const float* __restrict__ node_attr,
    const float* __restrict__ edge_attr,
    const float* __restrict__ edge_vec,
    const float* __restrict__ fc1_b,
    const float* __restrict__ fc2_b,
    const short* __restrict__ wpack,
    const int*   __restrict__ edge_index,
    float* __restrict__ msg,       // [E][32] CSR-ordered messages
    int*   __restrict__ cursor,
    int E)
{
    __shared__ __align__(16) short smemS[SMEM_HW];
    float* smemF = (float*)smemS;
    int*   smemI = (int*)smemS;
    const int tid = threadIdx.x;
    const int base = blockIdx.x * TB;
    const int l  = tid & 63;
    const int wv = tid >> 6;
    const int g  = l >> 4;
    const int c  = l & 15;
    const int rb = wv * 32;

    // ---- W + bias staging: prepacked -> linear copy (cross-wave, needs barrier)
    for (int idx = tid; idx < 2944; idx += THREADS)
        *(float4*)&smemS[idx * 8] = ((const float4*)wpack)[idx];
    if (tid < 48) smemF[B1F + tid] = fc1_b[tid];
    for (int idx = tid; idx < 320; idx += THREADS) smemF[B2F + idx] = fc2_b[idx];

    // ---- per-edge staging: 2 threads/edge, wave-private rows ----
    {
        const int r = tid >> 1, h = tid & 1;
        const int e = base + r;
        const int ce = e < E ? e : (E - 1);
        const int dI = edge_index[E + ce];
        const float* ap = edge_attr + (size_t)ce * H + h * 24;
        float4 A0 = *(const float4*)(ap + 0);
        float4 A1 = *(const float4*)(ap + 4);
        float4 A2 = *(const float4*)(ap + 8);
        float4 A3 = *(const float4*)(ap + 12);
        float4 A4 = *(const float4*)(ap + 16);
        float4 A5 = *(const float4*)(ap + 20);
        const float* xp = node_attr + (size_t)dI * NS + h * 8;
        float4 X0 = *(const float4*)(xp + 0);
        float4 X1 = *(const float4*)(xp + 4);
        if (e >= E) {
            A0 = make_float4(0,0,0,0); A1 = A0; A2 = A0; A3 = A0; A4 = A0; A5 = A0;
            X0 = A0; X1 = A0;
        }
        const int s8 = (r & 7) << 3;
        int a = ATO + r * 64 + (((h*3 + 0) << 3) ^ s8);
        *(short4*)&smemS[a + 0] = make_short4(f2bf(A0.x), f2bf(A0.y), f2bf(A0.z), f2bf(A0.w));
        *(short4*)&smemS[a + 4] = make_short4(f2bf(A1.x), f2bf(A1.y), f2bf(A1.z), f2bf(A1.w));
        a = ATO + r * 64 + (((h*3 + 1) << 3) ^ s8);
        *(short4*)&smemS[a + 0] = make_short4(f2bf(A2.x), f2bf(A2.y), f2bf(A2.z), f2bf(A2.w));
        *(short4*)&smemS[a + 4] = make_short4(f2bf(A3.x), f2bf(A3.y), f2bf(A3.z), f2bf(A3.w));
        a = ATO + r * 64 + (((h*3 + 2) << 3) ^ s8);
        *(short4*)&smemS[a + 0] = make_short4(f2bf(A4.x), f2bf(A4.y), f2bf(A4.z), f2bf(A4.w));
        *(short4*)&smemS[a + 4] = make_short4(f2bf(A5.x), f2bf(A5.y), f2bf(A5.z), f2bf(A5.w));
        {
            short4 z = make_short4(0,0,0,0);
            int az = ATO + r * 64 + (((6 + h) << 3) ^ s8);
            *(short4*)&smemS[az + 0] = z; *(short4*)&smemS[az + 4] = z;
        }
        *(short4*)&smemS[XO + r * 16 + h * 8 + 0] =
            make_short4(f2bf(X0.x), f2bf(X0.y), f2bf(X0.z), f2bf(X0.w));
        *(short4*)&smemS[XO + r * 16 + h * 8 + 4] =
            make_short4(f2bf(X1.x), f2bf(X1.y), f2bf(X1.z), f2bf(X1.w));
        if (h == 0) {
            int sI = edge_index[ce];
            float vx = 0.f, vy = 0.f, vz = 0.f;
            if (e < E) {
                vx = edge_vec[3 * (size_t)ce + 0];
                vy = edge_vec[3 * (size_t)ce + 1];
                vz = edge_vec[3 * (size_t)ce + 2];
            } else sI = 0;
            float rn = 1.0f / (sqrtf(vx*vx + vy*vy + vz*vz) + 1e-8f);
            const float c1 = 1.7320508075688772f;
            *(float4*)&smemF[SVFI + r * 4] =
                make_float4(c1*vx*rn, c1*vy*rn, c1*vz*rn, __int_as_float(sI));
            int slot = 0;
            if (e < E) slot = atomicAdd(cursor + sI, 1);
            smemI[SLII + r] = slot;
        }
    }
    __syncthreads();

    // ---- GEMM1: T = relu(A @ W1 + b1) ----
    bf16x8 a0[2], a1[2];
    #pragma unroll
    for (int m = 0; m < 2; ++m) {
        int row = rb + m * 16 + c, s8 = (row & 7) << 3;
        a0[m] = *(const bf16x8*)&smemS[ATO + row * 64 + ((g * 8) ^ s8)];
        a1[m] = *(const bf16x8*)&smemS[ATO + row * 64 + ((32 + g * 8) ^ s8)];
    }
    #pragma unroll
    for (int fr = 0; fr < 3; ++fr) {
        bf16x8 b0 = *(const bf16x8*)&smemS[WO + fr * 1024 + l * 8];
        bf16x8 b1 = *(const bf16x8*)&smemS[WO + fr * 1024 + 512 + l * 8];
        float bia = smemF[B1F + fr * 16 + c];
        #pragma unroll
        for (int m = 0; m < 2; ++m) {
            f32x4 acc = {0.f, 0.f, 0.f, 0.f};
            acc = __builtin_amdgcn_mfma_f32_16x16x32_bf16(a0[m], b0, acc, 0, 0, 0);
            acc = __builtin_amdgcn_mfma_f32_16x16x32_bf16(a1[m], b1, acc, 0, 0, 0);
            #pragma unroll
            for (int j = 0; j < 4; ++j) {
                int row = rb + m * 16 + g * 4 + j;
                smemS[ATO + row * 64 + ((fr * 16 + c) ^ ((row & 7) << 3))] =
                    f2bf(fmaxf(acc[j] + bia, 0.f));
            }
        }
    }

    // ---- fragments for GEMM2 ----
    bf16x8 tf0[2], tf1[2];
    #pragma unroll
    for (int m = 0; m < 2; ++m) {
        int row = rb + m * 16 + c, s8 = (row & 7) << 3;
        tf0[m] = *(const bf16x8*)&smemS[ATO + row * 64 + ((g * 8) ^ s8)];
        tf1[m] = *(const bf16x8*)&smemS[ATO + row * 64 + ((32 + g * 8) ^ s8)];
    }
    bf16x8 xr0[2][4], xr1[2][4];
    #pragma unroll
    for (int m = 0; m < 2; ++m)
        #pragma unroll
        for (int j = 0; j < 4; ++j) {
            int row = rb + m * 16 + g * 4 + j;
            xr0[m][j] = *(const bf16x8*)&smemS[XO + row * 16];
            xr1[m][j] = *(const bf16x8*)&smemS[XO + row * 16 + 8];
        }

    // ---- GEMM2 + fused contraction with x ----
    float o0[2][4] = {{0.f,0.f,0.f,0.f},{0.f,0.f,0.f,0.f}};
    float o1[2][4] = {{0.f,0.f,0.f,0.f},{0.f,0.f,0.f,0.f}};
    const int s2 = c >> 2;
    #pragma unroll
    for (int u = 0; u < 20; ++u) {
        bf16x8 b0 = *(const bf16x8*)&smemS[WO + (3 + u) * 1024 + l * 8];
        bf16x8 b1 = *(const bf16x8*)&smemS[WO + (3 + u) * 1024 + 512 + l * 8];
        float bia = smemF[B2F + u * 16 + c];
        #pragma unroll
        for (int m = 0; m < 2; ++m) {
            f32x4 acc = {0.f, 0.f, 0.f, 0.f};
            acc = __builtin_amdgcn_mfma_f32_16x16x32_bf16(tf0[m], b0, acc, 0, 0, 0);
            acc = __builtin_amdgcn_mfma_f32_16x16x32_bf16(tf1[m], b1, acc, 0, 0, 0);
            if (u < 16) {
                #pragma unroll
                for (int j = 0; j < 4; ++j) {
                    float xu = bf2f(u < 8 ? xr0[m][j][u] : xr1[m][j][u - 8]);
                    o0[m][j] = fmaf(xu, acc[j] + bia, o0[m][j]);
                }
            } else {
                const int f = u - 16;
                #pragma unroll
                for (int j = 0; j < 4; ++j) {
                    float e0, e1, e2, e3;
                    if (f < 2) {
                        e0 = bf2f(xr0[m][j][f*4+0]); e1 = bf2f(xr0[m][j][f*4+1]);
                        e2 = bf2f(xr0[m][j][f*4+2]); e3 = bf2f(xr0[m][j][f*4+3]);
                    } else {
                        e0 = bf2f(xr1[m][j][(f-2)*4+0]); e1 = bf2f(xr1[m][j][(f-2)*4+1]);
                        e2 = bf2f(xr1[m][j][(f-2)*4+2]); e3 = bf2f(xr1[m][j][(f-2)*4+3]);
                    }
                    float xu = e0;
                    xu = (s2 == 1) ? e1 : xu;
                    xu = (s2 == 2) ? e2 : xu;
                    xu = (s2 == 3) ? e3 : xu;
                    o1[m][j] = fmaf(xu, acc[j] + bia, o1[m][j]);
                }
            }
        }
    }
    #pragma unroll
    for (int m = 0; m < 2; ++m)
        #pragma unroll
        for (int j = 0; j < 4; ++j) {
            o1[m][j] += __shfl_xor(o1[m][j], 4);
            o1[m][j] += __shfl_xor(o1[m][j], 8);
        }

    // ---- epilogue: transpose messages through LDS (A region, now dead) ----
    const float inv = 0.25f;
    #pragma unroll
    for (int m = 0; m < 2; ++m)
        #pragma unroll
        for (int j = 0; j < 4; ++j) {
            const int r = rb + m*16 + g*4 + j;
            float4 sv = *(const float4*)&smemF[SVFI + r * 4];
            int lsrc = (g << 4) + (c < 12 ? c / 3 : 0);
            float ov = __shfl(o1[m][j], lsrc);
            int m3 = c - 3 * (c / 3);
            float shm = (m3 == 0) ? sv.x : ((m3 == 1) ? sv.y : sv.z);
            float v2 = (c < 12) ? ov * shm * inv : 0.f;
            smemF[MSGF + r * 32 + c]      = o0[m][j] * inv;
            smemF[MSGF + r * 32 + 16 + c] = v2;
        }

    // ---- full-line stores: 8 lanes x float4 = one fully-dirty 128B line/edge ----
    #pragma unroll
    for (int it = 0; it < 4; ++it) {
        int r2 = rb + it * 8 + (l >> 3);
        int ch = (l & 7) * 4;
        int e2 = base + r2;
        int slot = smemI[SLII + r2];
        float4 val = *(const float4*)&smemF[MSGF + r2 * 32 + ch];
        if (e2 < E) *(float4*)(msg + (size_t)slot * 32 + ch) = val;
    }
}

__global__ __launch_bounds__(256) void hist_kernel(
    const int* __restrict__ edge_index, int* __restrict__ deg, int E)
{
    int i = blockIdx.x * blockDim.x + threadIdx.x;
    if (i < E) atomicAdd(deg + edge_index[i], 1);
}

// Unordered CSR offsets: block-local scan + one atomic base per block.
// Node segments need only be contiguous & disjoint, NOT id-ordered.
__global__ __launch_bounds__(1024) void offsets_kernel(
    const int* __restrict__ deg, int* __restrict__ starts,
    int* __restrict__ cursor, int* __restrict__ gtotal, int N)
{
    __shared__ int lds[1024];
    __shared__ int base_s;
    const int t = threadIdx.x;
    const int i = blockIdx.x * 1024 + t;
    int v = (i < N) ? deg[i] : 0;
    lds[t] = v;
    __syncthreads();
    int acc = v;
    for (int off = 1; off < 1024; off <<= 1) {
        int u = (t >= off) ? lds[t - off] : 0;
        __syncthreads();
        acc += u;
        lds[t] = acc;
        __syncthreads();
    }
    if (t == 1023) base_s = atomicAdd(gtotal, acc);
    __syncthreads();
    int excl = acc - v;
    if (i < N) {
        int s = base_s + excl;
        starts[i] = s;
        cursor[i] = s;
    }
}

// one wave per node; CSR rows contiguous -> streaming reads
__global__ __launch_bounds__(256) void sum_kernel(
    const float* __restrict__ msg, const int* __restrict__ starts,
    const int* __restrict__ deg, float* __restrict__ out, int N)
{
    int w = (blockIdx.x * blockDim.x + threadIdx.x) >> 6;
    int l = threadIdx.x & 63;
    int half = l >> 5, ch = l & 31;
    if (w >= N) return;
    int s = starts[w], d = deg[w];
    float acc = 0.f;
    for (int k = half; k < d; k += 2)
        acc += msg[(size_t)(s + k) * 32 + ch];
    acc += __shfl_xor(acc, 32);
    if (l < 28) out[(size_t)w * 28 + l] = acc / fmaxf((float)d, 1.0f);
}

__global__ __launch_bounds__(256) void finalize_kernel(
    float* __restrict__ out, const float* __restrict__ cnt, int total)
{
    int i = blockIdx.x * blockDim.x + threadIdx.x;
    if (i < total) {
        float cv = cnt[i / 28];
        out[i] = out[i] / fmaxf(cv, 1.0f);
    }
}

// compact fp32 fallback (only if workspace is unexpectedly small)
__global__ __launch_bounds__(256) void naive_kernel(
    const float* __restrict__ node_attr, const float* __restrict__ edge_attr,
    const float* __restrict__ edge_vec, const float* __restrict__ fc1_w,
    const float* __restrict__ fc1_b, const float* __restrict__ fc2_w,
    const float* __restrict__ fc2_b, const int* __restrict__ edge_index,
    float* __restrict__ out, float* __restrict__ cnt, int E)
{
    int e = blockIdx.x * blockDim.x + threadIdx.x;
    if (e >= E) return;
    float a[H];
    for (int i = 0; i < H; ++i) a[i] = edge_attr[(size_t)e*H + i];
    int dst = edge_index[E + e];
    float x[NS];
    for (int i = 0; i < NS; ++i) x[i] = node_attr[(size_t)dst*NS + i];
    float o0[NS] = {0}, o1v[4] = {0};
    for (int k = 0; k < H; ++k) {
        float tk = fc1_b[k];
        for (int j = 0; j < H; ++j) tk = fmaf(a[j], fc1_w[j*H + k], tk);
        tk = fmaxf(tk, 0.f);
        const float* row = fc2_w + k*320;
        for (int u = 0; u < NS; ++u) {
            float q = tk * x[u];
            for (int w = 0; w < NS; ++w) o0[w] = fmaf(q, row[u*NS+w], o0[w]);
            for (int v = 0; v < 4; ++v) o1v[v] = fmaf(q, row[256+u*4+v], o1v[v]);
        }
    }
    for (int u = 0; u < NS; ++u) {
        float xu = x[u];
        for (int w = 0; w < NS; ++w) o0[w] = fmaf(xu, fc2_b[u*NS+w], o0[w]);
        for (int v = 0; v < 4; ++v) o1v[v] = fmaf(xu, fc2_b[256+u*4+v], o1v[v]);
    }
    float vx = edge_vec[3*(size_t)e], vy = edge_vec[3*(size_t)e+1], vz = edge_vec[3*(size_t)e+2];
    float rn = 1.0f / (sqrtf(vx*vx+vy*vy+vz*vz) + 1e-8f);
    const float c1 = 1.7320508075688772f;
    float sx = c1*vx*rn, sy = c1*vy*rn, sz = c1*vz*rn;
    int src = edge_index[e];
    float* ob = out + (size_t)src * 28;
    for (int w = 0; w < NS; ++w) atomicAdd(ob + w, o0[w] * 0.25f);
    for (int v = 0; v < 4; ++v) {
        float q = o1v[v] * 0.25f;
        atomicAdd(ob + 16 + 3*v + 0, q * sx);
        atomicAdd(ob + 16 + 3*v + 1, q * sy);
        atomicAdd(ob + 16 + 3*v + 2, q * sz);
    }
    atomicAdd(cnt + src, 1.0f);
}

extern "C" void kernel_launch(void* const* d_in, const int* in_sizes, int n_in,
                              void* d_out, int out_size, void* d_ws, size_t ws_size,
                              hipStream_t stream) {
    const float* node_attr  = (const float*)d_in[0];
    const float* edge_attr  = (const float*)d_in[1];
    const float* edge_vec   = (const float*)d_in[2];
    const float* fc1_w      = (const float*)d_in[3];
    const float* fc1_b      = (const float*)d_in[4];
    const float* fc2_w      = (const float*)d_in[5];
    const float* fc2_b      = (const float*)d_in[6];
    const int*   edge_index = (const int*)d_in[7];

    int E = in_sizes[2] / 3;      // 400000
    int N = in_sizes[0] / NS;     // 50000
    float* out = (float*)d_out;
    int nblk = (E + TB - 1) / TB;

    size_t msg_b  = (size_t)E * 32 * sizeof(float);
    size_t ints_b = (3 * (size_t)N + 1) * sizeof(int);
    size_t wpk_b  = 23 * 1024 * sizeof(short);
    size_t need   = msg_b + ints_b + wpk_b;

    if (ws_size >= need) {
        float* msg  = (float*)d_ws;
        int* ip     = (int*)((char*)d_ws + msg_b);
        int* deg    = ip;
        int* starts = ip + N;
        int* cursor = ip + 2 * N;
        int* gtotal = ip + 3 * N;
        short* wpack = (short*)((char*)d_ws + msg_b + ints_b);

        hipMemsetAsync(deg, 0, (size_t)N * sizeof(int), stream);
        hipMemsetAsync(gtotal, 0, sizeof(int), stream);
        prep_kernel<<<6, 256, 0, stream>>>(fc1_w, fc2_w, wpack);
        hist_kernel<<<(E + 255) / 256, 256, 0, stream>>>(edge_index, deg, E);
        offsets_kernel<<<(N + 1023) / 1024, 1024, 0, stream>>>(
            deg, starts, cursor, gtotal, N);
        edge_mfma_kernel<<<nblk, THREADS, 0, stream>>>(
            node_attr, edge_attr, edge_vec, fc1_b, fc2_b, wpack,
            edge_index, msg, cursor, E);
        sum_kernel<<<((size_t)N * 64 + 255) / 256, 256, 0, stream>>>(
            msg, starts, deg, out, N);
    } else {
        float* cnt = (float*)d_ws;
        hipMemsetAsync(d_out, 0, (size_t)out_size * sizeof(float), stream);
        hipMemsetAsync(d_ws, 0, (size_t)N * sizeof(float), stream);
        naive_kernel<<<(E + 255) / 256, 256, 0, stream>>>(
            node_attr, edge_attr, edge_vec, fc1_w, fc1_b, fc2_w, fc2_b,
            edge_index, out, cnt, E);
        int total = N * 28;
        finalize_kernel<<<(total + 255) / 256, 256, 0, stream>>>(out, cnt, total);
    }
}